// Round 1
// baseline (480.578 us; speedup 1.0000x reference)
//
#include <hip/hip_runtime.h>
#include <hip/hip_bf16.h>
#include <stdint.h>

// MFMA fragment types (gfx950: mfma_f32_16x16x32_bf16 takes <8 x bf16>)
typedef __bf16 bf16x8 __attribute__((ext_vector_type(8)));
typedef float  f32x4  __attribute__((ext_vector_type(4)));

#define MFMA(A, B, C) __builtin_amdgcn_mfma_f32_16x16x32_bf16((A), (B), (C), 0, 0, 0)

// fp32 -> bf16 round-to-nearest-even
static __device__ __forceinline__ unsigned short f2b(float f) {
    union { float f; unsigned int u; } v; v.f = f;
    return (unsigned short)((v.u + 0x7FFFu + ((v.u >> 16) & 1u)) >> 16);
}

// ---------------------------------------------------------------------------
// Kernel 1: x fp32 -> bf16 [N+1][128]; zero pad row N of x_bf16 and h_comb.
// ---------------------------------------------------------------------------
__global__ __launch_bounds__(256) void convert_kernel(
    const float* __restrict__ x, unsigned short* __restrict__ xb,
    unsigned short* __restrict__ hb, int N) {
    long long i = (long long)blockIdx.x * blockDim.x + threadIdx.x; // 4 elems each
    long long base = i * 4;
    long long nx = (long long)N * 128;
    long long total = nx + 128;
    if (base >= total) return;
    if (base < nx) {
        float4 v = *(const float4*)(x + base);
        ushort4 o;
        o.x = f2b(v.x); o.y = f2b(v.y); o.z = f2b(v.z); o.w = f2b(v.w);
        *(ushort4*)(xb + base) = o;
    } else {
        ushort4 z = make_ushort4(0, 0, 0, 0);
        *(ushort4*)(xb + base) = z;   // pad row (index == N -> zeros)
        *(ushort4*)(hb + base) = z;
    }
}

// ---------------------------------------------------------------------------
// Kernel 2: pack weights into MFMA B-fragment order.
// Layout: wp[((s*4 + t)*64 + lane)*8 + j] = W[k][cinb + q*8 + j][t*16 + n16]
//   where q=lane>>4, n16=lane&15, k=s/cinSteps, cinb=(s%cinSteps)*32.
// Group counts: wp00 108*4*64=27648, wp01 54*4*64=13824, wp11 13824,
//               wp10 4*4*64=1024, wp12 2*4*64=512  -> 56832 threads total.
// ---------------------------------------------------------------------------
__global__ __launch_bounds__(256) void pack_kernel(
    const float* __restrict__ W00, const float* __restrict__ W01,
    const float* __restrict__ W10, const float* __restrict__ W11,
    const float* __restrict__ W12,
    unsigned short* __restrict__ wp00, unsigned short* __restrict__ wp01,
    unsigned short* __restrict__ wp10, unsigned short* __restrict__ wp11,
    unsigned short* __restrict__ wp12) {
    int g = blockIdx.x * blockDim.x + threadIdx.x;
    const float* W; unsigned short* out; int cinSteps;
    if (g < 27648)      { W = W00; out = wp00; cinSteps = 4; }
    else if (g < 41472) { g -= 27648; W = W01; out = wp01; cinSteps = 2; }
    else if (g < 55296) { g -= 41472; W = W11; out = wp11; cinSteps = 2; }
    else if (g < 56320) { g -= 55296; W = W10; out = wp10; cinSteps = 4; }
    else if (g < 56832) { g -= 56320; W = W12; out = wp12; cinSteps = 2; }
    else return;
    int lane = g & 63;
    int st   = g >> 6;
    int t    = st & 3;
    int s    = st >> 2;
    int q = lane >> 4, n16 = lane & 15;
    int k    = s / cinSteps;
    int cinb = (s % cinSteps) * 32;
    int Cin  = cinSteps * 32;
    int cout = t * 16 + n16;
    unsigned short o[8];
#pragma unroll
    for (int j = 0; j < 8; ++j) {
        float v = W[(size_t)(k * Cin + cinb + q * 8 + j) * 64 + cout];
        o[j] = f2b(v);
    }
    *(ushort4*)(out + (size_t)g * 8)     = make_ushort4(o[0], o[1], o[2], o[3]);
    *(ushort4*)(out + (size_t)g * 8 + 4) = make_ushort4(o[4], o[5], o[6], o[7]);
}

// ---------------------------------------------------------------------------
// Pass B: h0 = relu(sparse_conv(x, W00, b00)); h1 = relu(x @ W10 + b10)
// Writes h_comb[N][128] bf16 = [h0 | h1].
// One wave = 32 rows (2 row-sets of 16) x 64 cout.
// ---------------------------------------------------------------------------
__global__ __launch_bounds__(256, 2) void passB_kernel(
    const unsigned short* __restrict__ xb, const int* __restrict__ nbr,
    const unsigned short* __restrict__ wp00, const unsigned short* __restrict__ wp10,
    const float* __restrict__ b00, const float* __restrict__ b10,
    unsigned short* __restrict__ hb, int N) {
    int lane = threadIdx.x & 63;
    int wv   = threadIdx.x >> 6;
    int q = lane >> 4, n16 = lane & 15;
    int rowbase = blockIdx.x * 128 + wv * 32;

    f32x4 acc0[2][4];   // conv0_0 accum: [row-set][n-tile]
    f32x4 acc1[2][4];   // conv1_0 (1x1) accum
#pragma unroll
    for (int rs = 0; rs < 2; ++rs)
#pragma unroll
        for (int t = 0; t < 4; ++t) { acc0[rs][t] = (f32x4)0.f; acc1[rs][t] = (f32x4)0.f; }

    int mc0 = min(rowbase + n16, N - 1);        // A-row for row-set 0 (lane&15)
    int mc1 = min(rowbase + 16 + n16, N - 1);   // A-row for row-set 1

    for (int k = 0; k < 27; ++k) {
        int r0 = nbr[(size_t)mc0 * 27 + k];
        int r1 = nbr[(size_t)mc1 * 27 + k];
        const unsigned short* a0p = xb + (size_t)r0 * 128 + q * 8;
        const unsigned short* a1p = xb + (size_t)r1 * 128 + q * 8;
#pragma unroll
        for (int s2 = 0; s2 < 4; ++s2) {
            bf16x8 A0 = *(const bf16x8*)(a0p + s2 * 32);
            bf16x8 A1 = *(const bf16x8*)(a1p + s2 * 32);
            const unsigned short* bp = wp00 + ((size_t)(k * 4 + s2) * 4 * 64) * 8 + lane * 8;
#pragma unroll
            for (int t = 0; t < 4; ++t) {
                bf16x8 B = *(const bf16x8*)(bp + t * 512);
                acc0[0][t] = MFMA(A0, B, acc0[0][t]);
                acc0[1][t] = MFMA(A1, B, acc0[1][t]);
            }
        }
    }
    // fused 1x1 conv (own row, no gather)
    {
        const unsigned short* a0p = xb + (size_t)mc0 * 128 + q * 8;
        const unsigned short* a1p = xb + (size_t)mc1 * 128 + q * 8;
#pragma unroll
        for (int s2 = 0; s2 < 4; ++s2) {
            bf16x8 A0 = *(const bf16x8*)(a0p + s2 * 32);
            bf16x8 A1 = *(const bf16x8*)(a1p + s2 * 32);
            const unsigned short* bp = wp10 + (size_t)(s2 * 4) * 64 * 8 + lane * 8;
#pragma unroll
            for (int t = 0; t < 4; ++t) {
                bf16x8 B = *(const bf16x8*)(bp + t * 512);
                acc1[0][t] = MFMA(A0, B, acc1[0][t]);
                acc1[1][t] = MFMA(A1, B, acc1[1][t]);
            }
        }
    }
    // epilogue: bias, relu, -> bf16, store h_comb.  C-layout: col=lane&15, row=q*4+r
#pragma unroll
    for (int rs = 0; rs < 2; ++rs)
#pragma unroll
        for (int t = 0; t < 4; ++t) {
            int col = t * 16 + n16;
            float bb0 = b00[col], bb1 = b10[col];
#pragma unroll
            for (int r = 0; r < 4; ++r) {
                int row = rowbase + rs * 16 + q * 4 + r;
                if (row < N) {
                    float h0 = fmaxf(acc0[rs][t][r] + bb0, 0.f);
                    float h1 = fmaxf(acc1[rs][t][r] + bb1, 0.f);
                    hb[(size_t)row * 128 + col]      = f2b(h0);
                    hb[(size_t)row * 128 + 64 + col] = f2b(h1);
                }
            }
        }
}

// ---------------------------------------------------------------------------
// Pass C: out0 = sparse_conv(h0, W01, b01);  t = relu(sparse_conv(h1, W11, b11));
//         out1 = t @ W12 + b12;  out = [out0 | out1] + x   (fp32)
// Shares one gather of h_comb for both convs.
// ---------------------------------------------------------------------------
__global__ __launch_bounds__(256, 2) void passC_kernel(
    const unsigned short* __restrict__ hb, const int* __restrict__ nbr,
    const float* __restrict__ x,
    const unsigned short* __restrict__ wp01, const unsigned short* __restrict__ wp11,
    const unsigned short* __restrict__ wp12,
    const float* __restrict__ b01, const float* __restrict__ b11,
    const float* __restrict__ b12, float* __restrict__ out, int N) {
    // LDS for C-layout -> A-layout transform of t.  stride 72 elems (144 B):
    // 16 B reads land 8 accesses/bank uniformly -> no extra conflicts.
    __shared__ __align__(16) unsigned short lds[4 * 2 * 16 * 72];
    int lane = threadIdx.x & 63;
    int wv   = threadIdx.x >> 6;
    int q = lane >> 4, n16 = lane & 15;
    int rowbase = blockIdx.x * 128 + wv * 32;

    f32x4 accO0[2][4];  // out0 accum
    f32x4 accT[2][4];   // conv1_1 accum
#pragma unroll
    for (int rs = 0; rs < 2; ++rs)
#pragma unroll
        for (int t = 0; t < 4; ++t) { accO0[rs][t] = (f32x4)0.f; accT[rs][t] = (f32x4)0.f; }

    int mc0 = min(rowbase + n16, N - 1);
    int mc1 = min(rowbase + 16 + n16, N - 1);

    for (int k = 0; k < 27; ++k) {
        int r0 = nbr[(size_t)mc0 * 27 + k];
        int r1 = nbr[(size_t)mc1 * 27 + k];
        const unsigned short* g0 = hb + (size_t)r0 * 128;
        const unsigned short* g1 = hb + (size_t)r1 * 128;
#pragma unroll
        for (int s2 = 0; s2 < 2; ++s2) {
            bf16x8 A0 = *(const bf16x8*)(g0 + s2 * 32 + q * 8);        // h0 cols
            bf16x8 A1 = *(const bf16x8*)(g1 + s2 * 32 + q * 8);
            const unsigned short* bp = wp01 + ((size_t)(k * 2 + s2) * 4 * 64) * 8 + lane * 8;
#pragma unroll
            for (int t = 0; t < 4; ++t) {
                bf16x8 B = *(const bf16x8*)(bp + t * 512);
                accO0[0][t] = MFMA(A0, B, accO0[0][t]);
                accO0[1][t] = MFMA(A1, B, accO0[1][t]);
            }
            bf16x8 C0 = *(const bf16x8*)(g0 + 64 + s2 * 32 + q * 8);   // h1 cols
            bf16x8 C1 = *(const bf16x8*)(g1 + 64 + s2 * 32 + q * 8);
            const unsigned short* bp2 = wp11 + ((size_t)(k * 2 + s2) * 4 * 64) * 8 + lane * 8;
#pragma unroll
            for (int t = 0; t < 4; ++t) {
                bf16x8 B = *(const bf16x8*)(bp2 + t * 512);
                accT[0][t] = MFMA(C0, B, accT[0][t]);
                accT[1][t] = MFMA(C1, B, accT[1][t]);
            }
        }
    }

    // epilogue 1: out0 (+bias +residual, fp32), and t -> relu -> bf16 -> LDS
    unsigned short* myl = lds + (size_t)wv * (2 * 16 * 72);
#pragma unroll
    for (int rs = 0; rs < 2; ++rs)
#pragma unroll
        for (int t = 0; t < 4; ++t) {
            int col = t * 16 + n16;
            float bo = b01[col], bt = b11[col];
#pragma unroll
            for (int r = 0; r < 4; ++r) {
                int row = rowbase + rs * 16 + q * 4 + r;
                if (row < N)
                    out[(size_t)row * 128 + col] =
                        accO0[rs][t][r] + bo + x[(size_t)row * 128 + col];
                float tv = fmaxf(accT[rs][t][r] + bt, 0.f);
                myl[(rs * 16 + q * 4 + r) * 72 + col] = f2b(tv);
            }
        }
    __syncthreads();

    // mini-GEMM: out1 = relu(t) @ W12   (A from LDS in A-layout)
    f32x4 accO1[2][4];
#pragma unroll
    for (int rs = 0; rs < 2; ++rs)
#pragma unroll
        for (int t = 0; t < 4; ++t) accO1[rs][t] = (f32x4)0.f;
#pragma unroll
    for (int s2 = 0; s2 < 2; ++s2) {
        bf16x8 A0 = *(const bf16x8*)(myl + (0 * 16 + n16) * 72 + s2 * 32 + q * 8);
        bf16x8 A1 = *(const bf16x8*)(myl + (16 + n16) * 72 + s2 * 32 + q * 8);
        const unsigned short* bp = wp12 + (size_t)(s2 * 4) * 64 * 8 + lane * 8;
#pragma unroll
        for (int t = 0; t < 4; ++t) {
            bf16x8 B = *(const bf16x8*)(bp + t * 512);
            accO1[0][t] = MFMA(A0, B, accO1[0][t]);
            accO1[1][t] = MFMA(A1, B, accO1[1][t]);
        }
    }
#pragma unroll
    for (int rs = 0; rs < 2; ++rs)
#pragma unroll
        for (int t = 0; t < 4; ++t) {
            int col = t * 16 + n16;
            float bo = b12[col];
#pragma unroll
            for (int r = 0; r < 4; ++r) {
                int row = rowbase + rs * 16 + q * 4 + r;
                if (row < N)
                    out[(size_t)row * 128 + 64 + col] =
                        accO1[rs][t][r] + bo + x[(size_t)row * 128 + 64 + col];
            }
        }
}

// ---------------------------------------------------------------------------
extern "C" void kernel_launch(void* const* d_in, const int* in_sizes, int n_in,
                              void* d_out, int out_size, void* d_ws, size_t ws_size,
                              hipStream_t stream) {
    const float* x   = (const float*)d_in[0];
    const int*   nbr = (const int*)d_in[1];
    const float* W00 = (const float*)d_in[2];
    const float* b00 = (const float*)d_in[3];
    const float* W01 = (const float*)d_in[4];
    const float* b01 = (const float*)d_in[5];
    const float* W10 = (const float*)d_in[6];
    const float* b10 = (const float*)d_in[7];
    const float* W11 = (const float*)d_in[8];
    const float* b11 = (const float*)d_in[9];
    const float* W12 = (const float*)d_in[10];
    const float* b12 = (const float*)d_in[11];
    float* out = (float*)d_out;
    int N = in_sizes[0] / 128;   // 100000

    // workspace carve-up (all 256B-aligned)
    char* ws = (char*)d_ws;
    size_t cur = 0;
    unsigned short* xb = (unsigned short*)(ws + cur); cur += (size_t)(N + 1) * 128 * 2;
    unsigned short* hb = (unsigned short*)(ws + cur); cur += (size_t)(N + 1) * 128 * 2;
    unsigned short* wp00 = (unsigned short*)(ws + cur); cur += 27648 * 8 * 2;
    unsigned short* wp01 = (unsigned short*)(ws + cur); cur += 13824 * 8 * 2;
    unsigned short* wp11 = (unsigned short*)(ws + cur); cur += 13824 * 8 * 2;
    unsigned short* wp10 = (unsigned short*)(ws + cur); cur += 1024 * 8 * 2;
    unsigned short* wp12 = (unsigned short*)(ws + cur); cur += 512 * 8 * 2;

    long long cvt_groups = ((long long)N * 128 + 128) / 4;
    int cvt_blocks = (int)((cvt_groups + 255) / 256);
    convert_kernel<<<cvt_blocks, 256, 0, stream>>>(x, xb, hb, N);
    pack_kernel<<<222, 256, 0, stream>>>(W00, W01, W10, W11, W12,
                                         wp00, wp01, wp10, wp11, wp12);
    int blocks = (N + 127) / 128;
    passB_kernel<<<blocks, 256, 0, stream>>>(xb, nbr, wp00, wp10, b00, b10, hb, N);
    passC_kernel<<<blocks, 256, 0, stream>>>(hb, nbr, x, wp01, wp11, wp12,
                                             b01, b11, b12, out, N);
}